// Round 1
// baseline (158.861 us; speedup 1.0000x reference)
//
#include <hip/hip_runtime.h>

// TripleGenerator: segmented triu-combinations.
// out = [idx_i (12M) | idx_j (12M) | idx_k (12M)] int32, 144 MB pure-write.
//
// R5: fill-shaped writer. The harness's own 576MB poison fill sustains
// 6.7 TB/s on this buffer; R4's writer only ~2.3 TB/s. Differences removed
// this round: (1) per-iteration global gathers (starts[atom], tb[r]) are
// hoisted into LDS once per block, so the hot loop has no vmcnt on the
// store chain; (2) grid-stride loop replaced by one contiguous 3072-group
// chunk per block with a fully-unrolled 12-store body (ILP: 12 stores in
// flight per wave, like the fill kernel's unrolled body).

constexpr int K      = 16;                // neighbors/atom
constexpr int T_PER  = K * (K - 1) / 2;   // 120
constexpr int GROUPS = T_PER / 4;         // 30 int4 groups per atom
constexpr int BLK    = 256;
constexpr int ITERS  = 12;
constexpr int CHUNK  = BLK * ITERS;       // 3072 int4 groups per block (48 KB)

typedef int iv4 __attribute__((ext_vector_type(4)));

// Packed (u,v) template: entry r holds bytes {t=4r..4r+3} of pu in u[r], pv in v[r].
struct Tbl { unsigned u[GROUPS]; unsigned v[GROUPS]; };
constexpr Tbl make_tbl() {
    Tbl t{};
    int idx = 0;
    for (int a = 0; a < K; ++a)
        for (int b = a + 1; b < K; ++b) {
            t.u[idx / 4] |= (unsigned)a << ((idx % 4) * 8);
            t.v[idx / 4] |= (unsigned)b << ((idx % 4) * 8);
            ++idx;
        }
    return t;
}
__device__ constexpr Tbl TBL = make_tbl();

// Pass 1: starts[a] = lower_bound(pair_i, a). Exact match of cumsum(counts)-counts
// for sorted pair_i (incl. empty segments). ~5 us, fully parallel.
__global__ void starts_kernel(const int* __restrict__ pair_i, int* __restrict__ starts,
                              int n_atoms, int m) {
    int a = blockIdx.x * blockDim.x + threadIdx.x;
    if (a >= n_atoms) return;
    int lo = 0, hi = m;
    while (lo < hi) {
        int mid = (lo + hi) >> 1;
        if (pair_i[mid] < a) lo = mid + 1; else hi = mid;
    }
    starts[a] = lo;
}

// Pass 2: stream-specialized, one contiguous chunk per block.
__global__ __launch_bounds__(BLK)
void gen_split(const int* __restrict__ starts, int* __restrict__ out,
               int per_arr_groups) {
    const int s  = blockIdx.x % 3;   // stream id (mixes streams across XCDs)
    const int b  = blockIdx.x / 3;
    const int g0 = b * CHUNK;
    if (g0 >= per_arr_groups) return;

    iv4* __restrict__ o = (iv4*)out + (size_t)s * per_arr_groups;
    const bool full = (g0 + CHUNK) <= per_arr_groups;

    if (s == 0) {
        // idx_i: pure compute, no loads at all.
        if (full) {
            #pragma unroll
            for (int k = 0; k < ITERS; ++k) {
                const int g    = g0 + k * BLK + (int)threadIdx.x;
                const int atom = g / GROUPS;           // magic-mul const-div
                iv4 v; v[0] = atom; v[1] = atom; v[2] = atom; v[3] = atom;
                o[g] = v;
            }
        } else {
            for (int g = g0 + (int)threadIdx.x; g < per_arr_groups; g += BLK) {
                const int atom = g / GROUPS;
                iv4 v; v[0] = atom; v[1] = atom; v[2] = atom; v[3] = atom;
                o[g] = v;
            }
        }
        return;
    }

    // idx_j / idx_k: hoist every gather into LDS once per block.
    __shared__ int      s_st[CHUNK / GROUPS + 2];   // <=104 starts entries
    __shared__ unsigned s_tb[GROUPS];               // 120 B packed template
    const int gend = full ? (g0 + CHUNK) : per_arr_groups;
    const int a0   = g0 / GROUPS;
    const int a1   = (gend - 1) / GROUPS;
    const int na   = a1 - a0 + 1;
    if ((int)threadIdx.x < na)     s_st[threadIdx.x] = starts[a0 + (int)threadIdx.x];
    if ((int)threadIdx.x < GROUPS) s_tb[threadIdx.x] = (s == 1 ? TBL.u : TBL.v)[threadIdx.x];
    __syncthreads();

    if (full) {
        #pragma unroll
        for (int k = 0; k < ITERS; ++k) {
            const int g     = g0 + k * BLK + (int)threadIdx.x;
            const int atom  = g / GROUPS;
            const int r     = g - atom * GROUPS;
            const int start = s_st[atom - a0];       // LDS, broadcast-heavy
            const unsigned ub = s_tb[r];             // LDS, 30 distinct dwords/wave
            iv4 v;
            v[0] = start + (int)(ub & 0xff);
            v[1] = start + (int)((ub >> 8)  & 0xff);
            v[2] = start + (int)((ub >> 16) & 0xff);
            v[3] = start + (int)((ub >> 24) & 0xff);
            o[g] = v;
        }
    } else {
        for (int g = g0 + (int)threadIdx.x; g < gend; g += BLK) {
            const int atom  = g / GROUPS;
            const int r     = g - atom * GROUPS;
            const int start = s_st[atom - a0];
            const unsigned ub = s_tb[r];
            iv4 v;
            v[0] = start + (int)(ub & 0xff);
            v[1] = start + (int)((ub >> 8)  & 0xff);
            v[2] = start + (int)((ub >> 16) & 0xff);
            v[3] = start + (int)((ub >> 24) & 0xff);
            o[g] = v;
        }
    }
}

extern "C" void kernel_launch(void* const* d_in, const int* in_sizes, int n_in,
                              void* d_out, int out_size, void* d_ws, size_t ws_size,
                              hipStream_t stream) {
    const int* pair_i  = (const int*)d_in[0];
    const int  m       = in_sizes[0];   // n_atoms * K
    const int  n_atoms = m / K;         // 100,000

    int* out = (int*)d_out;
    const int per_arr_groups = n_atoms * GROUPS;   // 3,000,000

    int* starts = (int*)d_ws;                      // 400 KB of scratch
    {
        const int b1 = 256;
        starts_kernel<<<(n_atoms + b1 - 1) / b1, b1, 0, stream>>>(pair_i, starts, n_atoms, m);
    }

    // One contiguous 3072-group chunk per block; 977 blocks/stream.
    const int nbs  = (per_arr_groups + CHUNK - 1) / CHUNK;
    gen_split<<<3 * nbs, BLK, 0, stream>>>(starts, out, per_arr_groups);
}